// Round 9
// baseline (118.243 us; speedup 1.0000x reference)
//
#include <hip/hip_runtime.h>

#define TAU 3.0f
#define FIX 0.2f
#define NPED 1024              // N per batch (reference setup)
#define BLOCK 256
#define PEDS_PER_BLOCK (BLOCK / 8)   // 32 peds per block

// Pre-pass: pack (px,py,vx,vy) into a float4 table in d_ws (4 MB for B*N
// entries -> L2-resident). 8 MB traffic, ~1.3 us.
__global__ __launch_bounds__(256) void pack_kernel(
    const float2* __restrict__ p, const float2* __restrict__ v,
    float4* __restrict__ table, int total)
{
    const int i = blockIdx.x * 256 + threadIdx.x;
    if (i < total) {
        const float2 pp = p[i];
        const float2 vv = v[i];
        table[i] = make_float4(pp.x, pp.y, vv.x, vv.y);
    }
}

// Main: barrier-free pure streaming. 8-lane team per pedestrian, lane sub
// handles 4 neighbors (one int4+float4 stream chunk). Neighbor gathers are
// global_load_dwordx4 from the packed table (L2 hit). No LDS, no syncthreads,
// 8192 blocks -> block churn keeps the 64 MB idx/mask stream continuously
// in flight (the shape the 6.5 TB/s fill kernel uses).
__global__ __launch_bounds__(BLOCK) void rvo_kernel(
    const float4* __restrict__ table,    // packed (B*N,4) in d_ws
    const float*  __restrict__ v_desire, // (B,N,2)
    const int*    __restrict__ near_idx, // (B,N,32)
    const float*  __restrict__ mask_arr, // (B,N,32)
    const int*    __restrict__ cth,      // scalar
    float*        __restrict__ out)      // (B,N,2)
{
    const int tid  = threadIdx.x;
    const int sub  = tid & 7;            // 4-neighbor chunk within ped
    const int team = tid >> 3;           // ped within block
    const int pair = blockIdx.x * PEDS_PER_BLOCK + team;
    const int tbase = (pair >> 10) << 10;          // batch * NPED

    // stream loads: wave = 8 peds x 8 chunks = 1 KB contiguous per array
    const int4   i4 = ((const int4*)near_idx)[pair * 8 + sub];
    const float4 m4 = ((const float4*)mask_arr)[pair * 8 + sub];
    // team-uniform loads (8 lanes same address -> one transaction, L1/L2)
    const float4 self = table[pair];
    const float2 vd   = ((const float2*)v_desire)[pair];

    const float thr2 = (float)cth[0] * (float)cth[0];
    const float px = self.x, py = self.y;
    const float vdx = vd.x, vdy = vd.y;

    const int   idxs[4] = {i4.x, i4.y, i4.z, i4.w};
    const float ms[4]   = {m4.x, m4.y, m4.z, m4.w};

    float nx = 0.0f, ny = 0.0f;
    #pragma unroll
    for (int j = 0; j < 4; ++j) {
        const float4 nb = table[tbase + idxs[j]];  // L2-hit gather, 16B
        const float m = ms[j];
        // rel = self - nb*m, fused (self-neighbor: rp == 0 exactly)
        const float rpx = fmaf(-m, nb.x, px);
        const float rpy = fmaf(-m, nb.y, py);
        const float rvx = fmaf(-m, nb.z, vdx);
        const float rvy = fmaf(-m, nb.w, vdy);

        const float dpv = fmaf(rpx, rvx, rpy * rvy);
        const float dvv = fmaf(rvx, rvx, fmaf(rvy, rvy, 2e-6f));  // eps folded
        float t = dpv * __builtin_amdgcn_rcpf(dvv);
        t = fminf(fmaxf(t, 0.0f), TAU);

        const float cx = fmaf(t, rvx, rpx);
        const float cy = fmaf(t, rvy, rpy);
        const float md2 = fmaf(cx, cx, cy * cy);   // squared miss distance

        const float s = fmaf(rpx, rpx, rpy * rpy);
        // s>0 guard: self-neighbor (s==0) contributes exactly 0
        // (ref: 0/(0+1e-6) == 0). rsq rel-err ~1e-7 vs 9.25e-2 threshold.
        const float sel0 = (s > 0.0f) ? __builtin_amdgcn_rsqf(s) : 0.0f;
        const float w    = (md2 < thr2) ? m : 0.0f;    // m in {0,1} exactly
        const float sel  = sel0 * w;
        nx = fmaf(-rpy, sel, nx);
        ny = fmaf( rpx, sel, ny);
    }

    // width-8 reduction over sub (ds_bpermute, no LDS allocation needed)
    #pragma unroll
    for (int d = 4; d > 0; d >>= 1) {
        nx += __shfl_down(nx, d, 8);
        ny += __shfl_down(ny, d, 8);
    }

    if (sub == 0) {
        ((float2*)out)[pair] = make_float2(fmaf(nx, FIX, vdx),
                                           fmaf(ny, FIX, vdy));
    }
}

extern "C" void kernel_launch(void* const* d_in, const int* in_sizes, int n_in,
                              void* d_out, int out_size, void* d_ws, size_t ws_size,
                              hipStream_t stream) {
    const float* p_cur    = (const float*)d_in[0];
    const float* v_cur    = (const float*)d_in[1];
    const float* v_desire = (const float*)d_in[2];
    const int*   near_idx = (const int*)d_in[3];
    const float* mask_arr = (const float*)d_in[4];
    const int*   cth      = (const int*)d_in[5];
    float*       out      = (float*)d_out;
    float4*      table    = (float4*)d_ws;       // 4 MB packed table

    const int BN = in_sizes[0] / 2;              // B*N pedestrians = 262144

    pack_kernel<<<(BN + 255) / 256, 256, 0, stream>>>(
        (const float2*)p_cur, (const float2*)v_cur, table, BN);

    rvo_kernel<<<BN / PEDS_PER_BLOCK, BLOCK, 0, stream>>>(
        table, v_desire, near_idx, mask_arr, cth, out);
}

// Round 10
// 108.363 us; speedup vs baseline: 1.0912x; 1.0912x over previous
//
#include <hip/hip_runtime.h>

#define TAU 3.0f
#define FIX 0.2f
#define NPED 1024              // N per batch (reference setup)
#define PEDS_PER_BLOCK 512
#define BLOCK 512
#define GROUPS (BLOCK / 8)                      // 64 peds per pass
#define PASSES (PEDS_PER_BLOCK / GROUPS)        // 8

// Layout: 8 lanes per pedestrian (sub = tid&7), each lane handles 4 neighbors.
// LDS holds the batch's packed (px,py,vx,vy) table; gather is ds_read_b128.
// PEDS_PER_BLOCK=512: staging redundancy 2x (8 MB total vs 16 MB at 256) --
// R3's dose-response showed staging bytes are paid at stream rate, so fewer
// redundant stagings = less cold-phase traffic. 2 blocks/CU, 16 waves/CU.
__global__ __launch_bounds__(BLOCK) void rvo_kernel(
    const float* __restrict__ p_cur,     // (B,N,2)
    const float* __restrict__ v_cur,     // (B,N,2)
    const float* __restrict__ v_desire,  // (B,N,2)
    const int*   __restrict__ near_idx,  // (B,N,32)
    const float* __restrict__ mask_arr,  // (B,N,32)
    const int*   __restrict__ cth,       // scalar
    float*       __restrict__ out,       // (B,N,2)
    int N)
{
    __shared__ float4 table[NPED];

    const int tid    = threadIdx.x;
    const int bpb    = N / PEDS_PER_BLOCK;          // blocks per batch = 2
    const int batch  = blockIdx.x / bpb;
    const int pbase  = (blockIdx.x % bpb) * PEDS_PER_BLOCK;

    // ---- stage packed (p,v) table: one float4 pair per thread, no loop ----
    const float4* pb4 = (const float4*)(p_cur) + (size_t)batch * (NPED / 2);
    const float4* vb4 = (const float4*)(v_cur) + (size_t)batch * (NPED / 2);
    {
        const float4 pp = pb4[tid];     // peds 2*tid, 2*tid+1 positions
        const float4 vv = vb4[tid];
        table[2 * tid]     = make_float4(pp.x, pp.y, vv.x, vv.y);
        table[2 * tid + 1] = make_float4(pp.z, pp.w, vv.z, vv.w);
    }
    __syncthreads();

    const float thr2 = (float)cth[0] * (float)cth[0];

    const int sub  = tid & 7;        // which 4-neighbor chunk (k = sub*4..sub*4+3)
    const int pgrp = tid >> 3;       // 0..63: pedestrian within pass

    #pragma unroll
    for (int pass = 0; pass < PASSES; ++pass) {
        const int ped  = pbase + pass * GROUPS + pgrp;
        const size_t pair = (size_t)batch * N + ped;

        // broadcast per-ped scalars (8 lanes same address)
        const float4 self = table[ped];
        const float2 vd   = ((const float2*)v_desire)[pair];
        const float px = self.x, py = self.y;
        const float vdx = vd.x, vdy = vd.y;

        // coalesced vector loads: 32 idx/mask per ped = 8 int4/float4
        const int4   i4 = ((const int4*)near_idx)[pair * 8 + sub];
        const float4 m4 = ((const float4*)mask_arr)[pair * 8 + sub];
        const int   idxs[4] = {i4.x, i4.y, i4.z, i4.w};
        const float ms[4]   = {m4.x, m4.y, m4.z, m4.w};

        float nx = 0.0f, ny = 0.0f;
        #pragma unroll
        for (int j = 0; j < 4; ++j) {
            const float4 nb = table[idxs[j]];    // LDS gather, ds_read_b128
            const float m = ms[j];
            // rel = self - nb*m, fused (self-neighbor: rp == 0 exactly)
            const float rpx = fmaf(-m, nb.x, px);
            const float rpy = fmaf(-m, nb.y, py);
            const float rvx = fmaf(-m, nb.z, vdx);
            const float rvy = fmaf(-m, nb.w, vdy);

            const float dpv = fmaf(rpx, rvx, rpy * rvy);
            const float dvv = fmaf(rvx, rvx, fmaf(rvy, rvy, 2e-6f)); // eps folded
            float t = dpv * __builtin_amdgcn_rcpf(dvv);
            t = fminf(fmaxf(t, 0.0f), TAU);      // inputs finite -> no NaN

            const float cx = fmaf(t, rvx, rpx);
            const float cy = fmaf(t, rvy, rpy);
            const float md2 = fmaf(cx, cx, cy * cy);   // squared miss dist

            const float s = fmaf(rpx, rpx, rpy * rpy);
            // s>0 guard: self-neighbor (s==0) contributes exactly 0
            // (ref: 0/(0+1e-6) == 0). rsq rel-err ~1e-7 vs 9.25e-2 thr.
            const float sel0 = (s > 0.0f) ? __builtin_amdgcn_rsqf(s) : 0.0f;
            const float w    = (md2 < thr2) ? m : 0.0f;  // m in {0,1}
            const float sel  = sel0 * w;
            nx = fmaf(-rpy, sel, nx);
            ny = fmaf( rpx, sel, ny);
        }

        // width-8 reduction over sub
        #pragma unroll
        for (int d = 4; d > 0; d >>= 1) {
            nx += __shfl_down(nx, d, 8);
            ny += __shfl_down(ny, d, 8);
        }

        if (sub == 0) {
            ((float2*)out)[pair] = make_float2(fmaf(nx, FIX, vdx),
                                               fmaf(ny, FIX, vdy));
        }
    }
}

extern "C" void kernel_launch(void* const* d_in, const int* in_sizes, int n_in,
                              void* d_out, int out_size, void* d_ws, size_t ws_size,
                              hipStream_t stream) {
    const float* p_cur    = (const float*)d_in[0];
    const float* v_cur    = (const float*)d_in[1];
    const float* v_desire = (const float*)d_in[2];
    const int*   near_idx = (const int*)d_in[3];
    const float* mask_arr = (const float*)d_in[4];
    const int*   cth      = (const int*)d_in[5];
    float*       out      = (float*)d_out;

    const int N  = NPED;
    const int BN = in_sizes[0] / 2;          // B*N pedestrians
    dim3 block(BLOCK);
    dim3 grid(BN / PEDS_PER_BLOCK);          // 512 blocks for B=256
    rvo_kernel<<<grid, block, 0, stream>>>(p_cur, v_cur, v_desire, near_idx,
                                           mask_arr, cth, out, N);
}